// Round 1
// baseline (432.447 us; speedup 1.0000x reference)
//
#include <hip/hip_runtime.h>

// Problem constants: NW=32 wavelets, N=M=1024.
#define NPOINTS 1048576ULL   // 1024*1024
#define NWV 32

// LDS address swizzle to break power-of-2-stride bank conflicts in the FFT:
// logical float2 index i -> physical i + (i>>4). Max 1023 -> 1086.
#define SW(i) ((i) + ((i) >> 4))

// ---------------------------------------------------------------------------
// Twiddle tables (inverse transform: W[k] = exp(+2*pi*i*k/1024)).
// Per-stage compacted layout so stage-s reads are at consecutive addresses:
//   stage s (len = 1024>>s) uses entries base_s + pos, pos < 512>>s,
//   value = W[pos << s];  base_s = 1024 - (1024>>s).  Total 1023 entries.
// ---------------------------------------------------------------------------
__global__ void k_init_tw(float2* __restrict__ tw) {
    int s    = blockIdx.x;            // 0..9
    int cnt  = 512 >> s;
    int base = 1024 - (1024 >> s);
    for (int k = threadIdx.x; k < cnt; k += blockDim.x) {
        double ang = 6.283185307179586232 * (double)(k << s) / 1024.0;
        tw[base + k] = make_float2((float)cos(ang), (float)sin(ang));
    }
}

// One DIF radix-2 butterfly on swizzled LDS array `a`, twiddle slice `tws`.
__device__ __forceinline__ void bfly(float2* a, const float2* tws, int j, int hb) {
    int half = 1 << hb;
    int pos  = j & (half - 1);
    int i0   = ((j >> hb) << (hb + 1)) | pos;
    int i1   = i0 + half;
    float2 u = a[SW(i0)], v = a[SW(i1)];
    float sx = u.x + v.x, sy = u.y + v.y;
    float dx = u.x - v.x, dy = u.y - v.y;
    float2 w = tws[pos];
    a[SW(i0)] = make_float2(sx, sy);
    a[SW(i1)] = make_float2(dx * w.x - dy * w.y, dx * w.y + dy * w.x);
}

// ---------------------------------------------------------------------------
// Pass A: per (wavelet, row): c = x_hat * psi (complex), scaled by 1/(N*M),
// 1024-pt inverse DIF FFT (bit-reversed output order, which is fine — see
// note below), write to T in 8-wide tiled layout T[wl][k>>3][n][k&7].
// ---------------------------------------------------------------------------
__global__ __launch_bounds__(256) void k_rowfft(
    const float2* __restrict__ xhat,
    const float*  __restrict__ pre,
    const float*  __restrict__ pim,
    const float2* __restrict__ twg,
    float2* __restrict__ T, int wbase)
{
    __shared__ float2 a[1088];     // 1024 swizzled
    __shared__ float2 tw[1023];
    const int t  = threadIdx.x;
    const int n  = blockIdx.x;
    const int wl = blockIdx.y;
    const int w  = wbase + wl;

    for (int i = t; i < 1023; i += 256) tw[i] = twg[i];

    const float4* x4  = (const float4*)(xhat + (size_t)n * 1024);
    const float4* pr4 = (const float4*)(pre + (size_t)w * NPOINTS + (size_t)n * 1024);
    const float4* pi4 = (const float4*)(pim + (size_t)w * NPOINTS + (size_t)n * 1024);
    float4 xa = x4[2 * t], xb = x4[2 * t + 1];
    float4 pr = pr4[t],    pi = pi4[t];
    const float s = 1.0f / 1048576.0f;   // ifft2 1/(N*M), exact pow2
    int k = t << 2;
    a[SW(k + 0)] = make_float2((xa.x * pr.x - xa.y * pi.x) * s, (xa.y * pr.x + xa.x * pi.x) * s);
    a[SW(k + 1)] = make_float2((xa.z * pr.y - xa.w * pi.y) * s, (xa.w * pr.y + xa.z * pi.y) * s);
    a[SW(k + 2)] = make_float2((xb.x * pr.z - xb.y * pi.z) * s, (xb.y * pr.z + xb.x * pi.z) * s);
    a[SW(k + 3)] = make_float2((xb.z * pr.w - xb.w * pi.w) * s, (xb.w * pr.w + xb.z * pi.w) * s);
    __syncthreads();

    for (int stage = 0; stage < 10; ++stage) {
        int hb = 9 - stage;
        const float2* tws = tw + (1024 - (1024 >> stage));
        bfly(a, tws, t, hb);
        bfly(a, tws, t + 256, hb);
        __syncthreads();
    }

    // Tiled write: element k -> T[wl][k>>3][n][k&7]; 8 lanes = 64B contiguous.
    float2* Tt = T + (size_t)wl * NPOINTS;
    #pragma unroll
    for (int r = 0; r < 4; ++r) {
        int kk = t + (r << 8);
        int kt = kk >> 3, kc = kk & 7;
        Tt[(((size_t)kt << 10) | (size_t)n) * 8 + kc] = a[SW(kk)];
    }
}

// ---------------------------------------------------------------------------
// Pass B: per (wavelet, 8-column tile): contiguous 64KB read of the tile,
// column FFTs in LDS (32 threads per column), modulus, write mod[w][p]
// with p = (kt*8+kc)*1024 + n.  Spatial order is a consistent permutation
// across wavelets -> Gram invariant.
// ---------------------------------------------------------------------------
#define PADC 1090
__global__ __launch_bounds__(256) void k_colfft(
    const float2* __restrict__ T,
    const float2* __restrict__ twg,
    float* __restrict__ modb, int wbase)
{
    __shared__ float2 col[8 * PADC];
    __shared__ float2 tw[1023];
    const int t  = threadIdx.x;
    const int kt = blockIdx.x;     // 0..127
    const int wl = blockIdx.y;
    const int w  = wbase + wl;

    for (int i = t; i < 1023; i += 256) tw[i] = twg[i];

    const float4* T4 = (const float4*)(T + (size_t)wl * NPOINTS + (size_t)kt * 8192);
    #pragma unroll
    for (int i = 0; i < 16; ++i) {
        int f = t + (i << 8);            // float4 index, covers float2 g=2f,2f+1
        float4 v = T4[f];
        int n  = f >> 2;
        int kc = (f << 1) & 7;           // even
        col[kc * PADC + SW(n)]       = make_float2(v.x, v.y);
        col[(kc + 1) * PADC + SW(n)] = make_float2(v.z, v.w);
    }
    __syncthreads();

    const int kc = t >> 5, u = t & 31;
    float2* c = col + kc * PADC;
    for (int stage = 0; stage < 10; ++stage) {
        int hb = 9 - stage;
        const float2* tws = tw + (1024 - (1024 >> stage));
        #pragma unroll
        for (int s = 0; s < 16; ++s)
            bfly(c, tws, u + (s << 5), hb);
        __syncthreads();
    }

    float* mo = modb + (size_t)w * NPOINTS + (size_t)kt * 8192;
    #pragma unroll
    for (int i = 0; i < 32; ++i) {
        int f = t + (i << 8);
        int kcc = f >> 10, n = f & 1023;
        float2 v = col[kcc * PADC + SW(n)];
        mo[f] = sqrtf(v.x * v.x + v.y * v.y + 1e-8f);
    }
}

// ---------------------------------------------------------------------------
// Pass C: Gram partials. Block = 1024 points; stage 32x256 tile in LDS;
// each 64-lane wave owns a 4x4 register block of the 32x32 Gram for its own
// point subset (wave = point phase). Deterministic partials, no atomics.
// ---------------------------------------------------------------------------
__global__ __launch_bounds__(256) void k_gram(
    const float* __restrict__ modb, float* __restrict__ part)
{
    __shared__ float tile[32][257];
    const int t = threadIdx.x;
    const int wave = t >> 6, l = t & 63;
    const int i0 = (l >> 3) << 2, j0 = (l & 7) << 2;
    float acc[4][4];
    #pragma unroll
    for (int ii = 0; ii < 4; ++ii)
        #pragma unroll
        for (int jj = 0; jj < 4; ++jj) acc[ii][jj] = 0.0f;

    const size_t pbase = (size_t)blockIdx.x << 10;
    for (int tt = 0; tt < 4; ++tt) {
        __syncthreads();
        size_t p0 = pbase + ((size_t)tt << 8);
        #pragma unroll
        for (int w = 0; w < 32; ++w)
            tile[w][t] = modb[((size_t)w << 20) + p0 + t];
        __syncthreads();
        #pragma unroll 4
        for (int p = 0; p < 64; ++p) {
            int pp = (p << 2) | wave;
            float ra0 = tile[i0 + 0][pp], ra1 = tile[i0 + 1][pp];
            float ra2 = tile[i0 + 2][pp], ra3 = tile[i0 + 3][pp];
            float rb0 = tile[j0 + 0][pp], rb1 = tile[j0 + 1][pp];
            float rb2 = tile[j0 + 2][pp], rb3 = tile[j0 + 3][pp];
            acc[0][0] += ra0 * rb0; acc[0][1] += ra0 * rb1; acc[0][2] += ra0 * rb2; acc[0][3] += ra0 * rb3;
            acc[1][0] += ra1 * rb0; acc[1][1] += ra1 * rb1; acc[1][2] += ra1 * rb2; acc[1][3] += ra1 * rb3;
            acc[2][0] += ra2 * rb0; acc[2][1] += ra2 * rb1; acc[2][2] += ra2 * rb2; acc[2][3] += ra2 * rb3;
            acc[3][0] += ra3 * rb0; acc[3][1] += ra3 * rb1; acc[3][2] += ra3 * rb2; acc[3][3] += ra3 * rb3;
        }
    }
    const int row = (blockIdx.x << 2) | wave;   // 4096 partial rows
    #pragma unroll
    for (int ii = 0; ii < 4; ++ii) {
        float4 v = make_float4(acc[ii][0], acc[ii][1], acc[ii][2], acc[ii][3]);
        *(float4*)&part[((size_t)row << 10) + (size_t)((i0 + ii) << 5) + j0] = v;
    }
}

// ---------------------------------------------------------------------------
// Pass D: reduce 4096 partial rows per Gram slot, map triangle index, scale
// by the einsum's 1/(N*M), write the 527 outputs.
// ---------------------------------------------------------------------------
__global__ __launch_bounds__(256) void k_reduce(
    const float* __restrict__ part, float* __restrict__ out)
{
    __shared__ float red[4];
    const int q = blockIdx.x, t = threadIdx.x;
    int i = 0, start = 0;
    while (start + (32 - i) <= q) { start += 32 - i; ++i; }
    int j = i + (q - start);
    int slot = (i << 5) | j;
    float v = 0.0f;
    for (int r = t; r < 4096; r += 256)
        v += part[((size_t)r << 10) + slot];
    #pragma unroll
    for (int off = 32; off; off >>= 1) v += __shfl_down(v, off);
    if ((t & 63) == 0) red[t >> 6] = v;
    __syncthreads();
    if (t == 0) out[q] = (red[0] + red[1] + red[2] + red[3]) * (1.0f / 1048576.0f);
}

// ---------------------------------------------------------------------------
extern "C" void kernel_launch(void* const* d_in, const int* in_sizes, int n_in,
                              void* d_out, int out_size, void* d_ws, size_t ws_size,
                              hipStream_t stream) {
    (void)in_sizes; (void)n_in;
    const float2* xhat = (const float2*)d_in[0];
    const float*  pre  = (const float*)d_in[1];
    const float*  pim  = (const float*)d_in[2];
    float* out = (float*)d_out;

    char* ws = (char*)d_ws;
    float2* tw   = (float2*)ws;                                          // 8.2 KB (1 MB slot)
    float*  modb = (float*)(ws + (1ULL << 20));                          // 128 MB
    float*  part = (float*)(ws + (1ULL << 20) + NWV * NPOINTS * 4ULL);   // 16 MB
    size_t  Toff = (1ULL << 20) + NWV * NPOINTS * 4ULL + 4096ULL * 1024ULL * 4ULL;
    float2* T    = (float2*)(ws + Toff);

    // Adaptive wavelet batch so T fits the workspace.
    int WB = 1;
    const int cands[6] = {32, 16, 8, 4, 2, 1};
    for (int c = 0; c < 6; ++c)
        if (Toff + (size_t)cands[c] * NPOINTS * 8ULL <= ws_size) { WB = cands[c]; break; }

    hipLaunchKernelGGL(k_init_tw, dim3(10), dim3(512), 0, stream, tw);
    for (int wb = 0; wb < NWV; wb += WB) {
        hipLaunchKernelGGL(k_rowfft, dim3(1024, WB), dim3(256), 0, stream,
                           xhat, pre, pim, (const float2*)tw, T, wb);
        hipLaunchKernelGGL(k_colfft, dim3(128, WB), dim3(256), 0, stream,
                           (const float2*)T, (const float2*)tw, modb, wb);
    }
    hipLaunchKernelGGL(k_gram, dim3(1024), dim3(256), 0, stream, modb, part);
    hipLaunchKernelGGL(k_reduce, dim3(out_size), dim3(256), 0, stream,
                       (const float*)part, out);
}

// Round 2
// 343.629 us; speedup vs baseline: 1.2585x; 1.2585x over previous
//
#include <hip/hip_runtime.h>

// NW=32 wavelets, N=M=1024.
#define NPOINTS 1048576ULL
#define NWV 32

// ---------------------------------------------------------------------------
// Compacted inverse-FFT twiddles, W_L^pos = exp(+2*pi*i*pos/L), L = 2^(hb+1).
// Stage hb (half = 2^hb) table: base = 1024 - 2^(hb+1), size 2^hb, hb = 9..2.
// Total 1020 float2.
// ---------------------------------------------------------------------------
__global__ void k_init_tw(float2* __restrict__ tw) {
    int hb   = 9 - blockIdx.x;              // 9..2
    int cnt  = 1 << hb;
    int base = 1024 - (2 << hb);
    for (int pos = threadIdx.x; pos < cnt; pos += 256) {
        double ang = 6.283185307179586232 * (double)pos / (double)(2 << hb);
        tw[base + pos] = make_float2((float)cos(ang), (float)sin(ang));
    }
}

__device__ __forceinline__ void bf(float2& a, float2& b, float2 w) {
    float sx = a.x + b.x, sy = a.y + b.y;
    float dx = a.x - b.x, dy = a.y - b.y;
    a = make_float2(sx, sy);
    b = make_float2(dx * w.x - dy * w.y, dx * w.y + dy * w.x);
}

// One 1024-pt inverse DIF FFT per 64-lane wave.
// In:  X[k] = element (l + 64k), natural order.
// Out: X[j] = output slot i = 64*(l>>2) + (l&3) + 4*j  (bit-reversed order —
//      a consistent spatial permutation, harmless for the Gram).
// exr/exi: this wave's private 1024-float LDS planes. One block barrier inside.
__device__ __forceinline__ void wave_fft(float2* X, int l,
    const float2* __restrict__ twl, float* exr, float* exi)
{
    // Phase 1: half = 512,256,128,64 — local over k.
    #pragma unroll
    for (int st = 0; st < 4; ++st) {
        const int step = 8 >> st;
        const float2* tb = twl + (1024 - (1024 >> st));
        #pragma unroll
        for (int g = 0; g < 16; g += 2 * step)
            #pragma unroll
            for (int c = 0; c < step; ++c)
                bf(X[g + c], X[g + c + step], tb[l + 64 * c]);
    }
    // Exchange (SoA, XOR-swizzled: phys = i ^ ((i>>6)<<2) — conflict-free).
    #pragma unroll
    for (int k = 0; k < 16; ++k) {
        int ph = 64 * k + (l ^ (k << 2));
        exr[ph] = X[k].x; exi[ph] = X[k].y;
    }
    __syncthreads();
    const int b = l >> 2, q = l & 3;
    float2 Y[16];
    #pragma unroll
    for (int j = 0; j < 16; ++j) {
        int ph = 64 * b + (((q + 4 * j) ^ (b << 2)) & 63);
        Y[j] = make_float2(exr[ph], exi[ph]);
    }
    // Phase 2: half = 32,16,8,4 — local over j (element i = 64b + q + 4j).
    #pragma unroll
    for (int st = 0; st < 4; ++st) {
        const int step = 8 >> st;
        const float2* tb = twl + (1024 - (64 >> st));
        #pragma unroll
        for (int g = 0; g < 16; g += 2 * step)
            #pragma unroll
            for (int c = 0; c < step; ++c)
                bf(Y[g + c], Y[g + c + step], tb[q + 4 * c]);
    }
    // half = 2: partner lane^2; twiddle 1 (q=2) or +i (q=3).
    #pragma unroll
    for (int j = 0; j < 16; ++j) {
        float ox = __shfl_xor(Y[j].x, 2);
        float oy = __shfl_xor(Y[j].y, 2);
        if ((l & 2) == 0) { Y[j].x += ox; Y[j].y += oy; }
        else {
            float dx = ox - Y[j].x, dy = oy - Y[j].y;
            Y[j] = (l & 1) ? make_float2(-dy, dx) : make_float2(dx, dy);
        }
    }
    // half = 1: partner lane^1; twiddle 1.
    #pragma unroll
    for (int j = 0; j < 16; ++j) {
        float ox = __shfl_xor(Y[j].x, 1);
        float oy = __shfl_xor(Y[j].y, 1);
        if ((l & 1) == 0) { Y[j].x += ox; Y[j].y += oy; }
        else { Y[j].x = ox - Y[j].x; Y[j].y = oy - Y[j].y; }
    }
    #pragma unroll
    for (int j = 0; j < 16; ++j) X[j] = Y[j];
}

// ---------------------------------------------------------------------------
// Pass A: 8 waves/block = rows n0..n0+7 of one wavelet. Pointwise complex
// multiply (scaled 1/2^20), wave FFT, block LDS transpose, write T[c][n]
// column-major (64B chunks per column).
// ---------------------------------------------------------------------------
__global__ __launch_bounds__(512, 4) void k_rowfft(
    const float2* __restrict__ xhat, const float* __restrict__ pre,
    const float* __restrict__ pim, const float2* __restrict__ twg,
    float2* __restrict__ T, int wbase)
{
    __shared__ float  ex[16448];      // 8 waves x 2 planes x 1028 floats
    __shared__ float2 twl[1020];
    const int t  = threadIdx.x;
    const int wv = t >> 6, l = t & 63;
    const int n  = blockIdx.x * 8 + wv;
    const int wl = blockIdx.y, w = wbase + wl;
    for (int i = t; i < 1020; i += 512) twl[i] = twg[i];
    float* exr = ex + wv * 2056;
    float* exi = exr + 1028;

    const float2* xr  = xhat + (size_t)n * 1024;
    const float*  prr = pre + (size_t)w * NPOINTS + (size_t)n * 1024;
    const float*  pir = pim + (size_t)w * NPOINTS + (size_t)n * 1024;
    float2 X[16];
    const float s = 1.0f / 1048576.0f;     // ifft2 1/(N*M)
    #pragma unroll
    for (int k = 0; k < 16; ++k) {
        float2 x = xr[l + 64 * k];
        float  a = prr[l + 64 * k], bb = pir[l + 64 * k];
        X[k] = make_float2((x.x * a - x.y * bb) * s, (x.y * a + x.x * bb) * s);
    }
    __syncthreads();                       // twiddles ready
    wave_fft(X, l, twl, exr, exi);

    // Transpose: wave writes its outputs (element i = 64b+q+4j) to its slice.
    const int b = l >> 2, q = l & 3;
    #pragma unroll
    for (int j = 0; j < 16; ++j) {
        int ph = 64 * b + (((q + 4 * j) ^ (b << 2)) & 63);
        exr[ph] = X[j].x; exi[ph] = X[j].y;
    }
    __syncthreads();
    // Emit T[c][n0..n0+7]: thread t -> (c = v*64 + t>>3, r = t&7).
    float2* Tw = T + (size_t)wl * NPOINTS;
    const int n0 = blockIdx.x * 8;
    const int u = t >> 3, r = t & 7;
    const float* sr = ex + r * 2056;
    const float* si = sr + 1028;
    #pragma unroll
    for (int v = 0; v < 16; ++v) {
        int c  = v * 64 + u;
        int ph = v * 64 + (u ^ (v << 2));
        Tw[(size_t)c * 1024 + n0 + r] = make_float2(sr[ph], si[ph]);
    }
}

// ---------------------------------------------------------------------------
// Pass B: 8 waves/block = 8 columns. Coalesced column reads (T is [c][n]),
// wave FFT, modulus, coalesced mod writes via lane-local permutation.
// ---------------------------------------------------------------------------
__global__ __launch_bounds__(512, 4) void k_colfft(
    const float2* __restrict__ T, const float2* __restrict__ twg,
    float* __restrict__ modb, int wbase)
{
    __shared__ float  ex[16448];
    __shared__ float2 twl[1020];
    const int t  = threadIdx.x;
    const int wv = t >> 6, l = t & 63;
    const int c  = blockIdx.x * 8 + wv;
    const int wl = blockIdx.y, w = wbase + wl;
    for (int i = t; i < 1020; i += 512) twl[i] = twg[i];
    float* exr = ex + wv * 2056;
    float* exi = exr + 1028;

    const float2* Tc = T + (size_t)wl * NPOINTS + (size_t)c * 1024;
    float2 X[16];
    #pragma unroll
    for (int k = 0; k < 16; ++k) X[k] = Tc[64 * k + l];
    __syncthreads();                       // twiddles ready
    wave_fft(X, l, twl, exr, exi);

    float* mo = modb + (size_t)w * NPOINTS + (size_t)c * 1024;
    #pragma unroll
    for (int j = 0; j < 16; ++j)
        mo[j * 64 + l] = sqrtf(X[j].x * X[j].x + X[j].y * X[j].y + 1e-8f);
}

// ---------------------------------------------------------------------------
// Pass C: Gram partials (unchanged). Deterministic, no atomics.
// ---------------------------------------------------------------------------
__global__ __launch_bounds__(256) void k_gram(
    const float* __restrict__ modb, float* __restrict__ part)
{
    __shared__ float tile[32][257];
    const int t = threadIdx.x;
    const int wave = t >> 6, l = t & 63;
    const int i0 = (l >> 3) << 2, j0 = (l & 7) << 2;
    float acc[4][4];
    #pragma unroll
    for (int ii = 0; ii < 4; ++ii)
        #pragma unroll
        for (int jj = 0; jj < 4; ++jj) acc[ii][jj] = 0.0f;

    const size_t pbase = (size_t)blockIdx.x << 10;
    for (int tt = 0; tt < 4; ++tt) {
        __syncthreads();
        size_t p0 = pbase + ((size_t)tt << 8);
        #pragma unroll
        for (int w = 0; w < 32; ++w)
            tile[w][t] = modb[((size_t)w << 20) + p0 + t];
        __syncthreads();
        #pragma unroll 4
        for (int p = 0; p < 64; ++p) {
            int pp = (p << 2) | wave;
            float ra0 = tile[i0 + 0][pp], ra1 = tile[i0 + 1][pp];
            float ra2 = tile[i0 + 2][pp], ra3 = tile[i0 + 3][pp];
            float rb0 = tile[j0 + 0][pp], rb1 = tile[j0 + 1][pp];
            float rb2 = tile[j0 + 2][pp], rb3 = tile[j0 + 3][pp];
            acc[0][0] += ra0 * rb0; acc[0][1] += ra0 * rb1; acc[0][2] += ra0 * rb2; acc[0][3] += ra0 * rb3;
            acc[1][0] += ra1 * rb0; acc[1][1] += ra1 * rb1; acc[1][2] += ra1 * rb2; acc[1][3] += ra1 * rb3;
            acc[2][0] += ra2 * rb0; acc[2][1] += ra2 * rb1; acc[2][2] += ra2 * rb2; acc[2][3] += ra2 * rb3;
            acc[3][0] += ra3 * rb0; acc[3][1] += ra3 * rb1; acc[3][2] += ra3 * rb2; acc[3][3] += ra3 * rb3;
        }
    }
    const int row = (blockIdx.x << 2) | wave;
    #pragma unroll
    for (int ii = 0; ii < 4; ++ii) {
        float4 v = make_float4(acc[ii][0], acc[ii][1], acc[ii][2], acc[ii][3]);
        *(float4*)&part[((size_t)row << 10) + (size_t)((i0 + ii) << 5) + j0] = v;
    }
}

// ---------------------------------------------------------------------------
// Pass D: reduce partials, map triangle index, apply einsum 1/(N*M).
// ---------------------------------------------------------------------------
__global__ __launch_bounds__(256) void k_reduce(
    const float* __restrict__ part, float* __restrict__ out)
{
    __shared__ float red[4];
    const int q = blockIdx.x, t = threadIdx.x;
    int i = 0, start = 0;
    while (start + (32 - i) <= q) { start += 32 - i; ++i; }
    int j = i + (q - start);
    int slot = (i << 5) | j;
    float v = 0.0f;
    for (int r = t; r < 4096; r += 256)
        v += part[((size_t)r << 10) + slot];
    #pragma unroll
    for (int off = 32; off; off >>= 1) v += __shfl_down(v, off);
    if ((t & 63) == 0) red[t >> 6] = v;
    __syncthreads();
    if (t == 0) out[q] = (red[0] + red[1] + red[2] + red[3]) * (1.0f / 1048576.0f);
}

// ---------------------------------------------------------------------------
extern "C" void kernel_launch(void* const* d_in, const int* in_sizes, int n_in,
                              void* d_out, int out_size, void* d_ws, size_t ws_size,
                              hipStream_t stream) {
    (void)in_sizes; (void)n_in;
    const float2* xhat = (const float2*)d_in[0];
    const float*  pre  = (const float*)d_in[1];
    const float*  pim  = (const float*)d_in[2];
    float* out = (float*)d_out;

    char* ws = (char*)d_ws;
    float2* tw   = (float2*)ws;                                   // 64 KB slot
    float*  modb = (float*)(ws + 65536);                          // 128 MB
    float*  part = (float*)(ws + 65536 + NWV * NPOINTS * 4ULL);   // 16 MB
    size_t  Toff = 65536 + NWV * NPOINTS * 4ULL + 4096ULL * 1024ULL * 4ULL;
    float2* T    = (float2*)(ws + Toff);

    // T batched over wavelets; WB=8 (64 MB) keeps T L3-resident.
    int WB = 1;
    const int cands[4] = {8, 4, 2, 1};
    for (int c = 0; c < 4; ++c)
        if (Toff + (size_t)cands[c] * NPOINTS * 8ULL <= ws_size) { WB = cands[c]; break; }

    hipLaunchKernelGGL(k_init_tw, dim3(8), dim3(256), 0, stream, tw);
    for (int wb = 0; wb < NWV; wb += WB) {
        hipLaunchKernelGGL(k_rowfft, dim3(128, WB), dim3(512), 0, stream,
                           xhat, pre, pim, (const float2*)tw, T, wb);
        hipLaunchKernelGGL(k_colfft, dim3(128, WB), dim3(512), 0, stream,
                           (const float2*)T, (const float2*)tw, modb, wb);
    }
    hipLaunchKernelGGL(k_gram, dim3(1024), dim3(256), 0, stream, modb, part);
    hipLaunchKernelGGL(k_reduce, dim3(out_size), dim3(256), 0, stream,
                       (const float*)part, out);
}